// Round 4
// baseline (42212.778 us; speedup 1.0000x reference)
//
#include <hip/hip_runtime.h>
#include <math.h>

// ---------------------------------------------------------------------------
// GameProcessor round 4: level-synchronous weight-stationary dataflow.
//   * 512 blocks x 1024 threads (2 blocks/CU, __launch_bounds__(1024,8) caps
//     VGPR<=64 so co-residency for the grid barrier is guaranteed).
//   * block b owns output dim d0=b for proj/gates; blocks 256-511 also own
//     one hidden unit (r_b,h_b) for the importance MLP.
//   * ALL mutable cross-block data (emb/ctx/nhbuf/hidbuf) accessed via
//     relaxed agent-scope atomics (write-through to LLC, cache-bypassing
//     reads) -> no acquire fences, no L1/L2 invalidation; immutable data
//     stays cached.
//   * barrier: distributed sense-epoch (release arr-flag per block on own
//     128B line; block0 polls in parallel, release-stores go; spinners poll
//     relaxed + compiler barrier).
// ---------------------------------------------------------------------------

#define NG   30000
#define NT   364
#define ND   512
#define NF   28
#define NH   128
#define NCIN 1053
#define NB   512
#define BLK  1024

__device__ __forceinline__ float sigmf(float x) { return 1.0f / (1.0f + expf(-x)); }

__device__ __forceinline__ float aload_f(const float* p) {
  return __hip_atomic_load(p, __ATOMIC_RELAXED, __HIP_MEMORY_SCOPE_AGENT);
}
__device__ __forceinline__ float2 aload_f2(const float* p) {
  unsigned long long u = __hip_atomic_load((const unsigned long long*)p,
      __ATOMIC_RELAXED, __HIP_MEMORY_SCOPE_AGENT);
  float2 v; __builtin_memcpy(&v, &u, 8); return v;
}
__device__ __forceinline__ void astore_f(float* p, float v) {
  __hip_atomic_store(p, v, __ATOMIC_RELAXED, __HIP_MEMORY_SCOPE_AGENT);
}
__device__ __forceinline__ void astore_f2(float* p, float x, float y) {
  float2 v = make_float2(x, y);
  unsigned long long u; __builtin_memcpy(&u, &v, 8);
  __hip_atomic_store((unsigned long long*)p, u, __ATOMIC_RELAXED, __HIP_MEMORY_SCOPE_AGENT);
}

__global__ void zero_kernel(int* p, int n) {
  int i = blockIdx.x * blockDim.x + threadIdx.x;
  if (i < n) p[i] = 0;
}

__global__ void deps_kernel(const int* __restrict__ ta, const int* __restrict__ tb,
                            int* __restrict__ dep0, int* __restrict__ dep1) {
  int g = blockIdx.x * blockDim.x + threadIdx.x;
  if (g >= NG) return;
  int a = ta[g], b = tb[g];
  int d0 = -1, d1 = -1;
  for (int p = g - 1; p >= 0; --p) {
    int pa = ta[p], pb = tb[p];
    if (d0 < 0 && (pa == a || pb == a)) d0 = p;
    if (d1 < 0 && (pa == b || pb == b)) d1 = p;
    if (d0 >= 0 && d1 >= 0) break;
  }
  dep0[g] = d0;
  dep1[g] = d1;
}

__global__ void levels_kernel(const int* __restrict__ d0a, const int* __restrict__ d1a,
                              int* __restrict__ level, int* __restrict__ nLevels) {
  __shared__ int lv[1024];
  __shared__ int changed;
  __shared__ int smax;
  const int tid = threadIdx.x;
  int localMax = 0;
  if (tid == 0) smax = 0;
  for (int base = 0; base < NG; base += 1024) {
    const int g = base + tid;
    const bool val = g < NG;
    int ic0 = -1, ic1 = -1, b = 0;
    if (val) {
      int d0 = d0a[g], d1 = d1a[g];
      if (d0 >= 0) { if (d0 < base) b = max(b, level[d0] + 1); else ic0 = d0 - base; }
      if (d1 >= 0) { if (d1 < base) b = max(b, level[d1] + 1); else ic1 = d1 - base; }
    }
    lv[tid] = b;
    __syncthreads();
    for (;;) {
      if (tid == 0) changed = 0;
      __syncthreads();
      int nl = lv[tid];
      if (ic0 >= 0) nl = max(nl, lv[ic0] + 1);
      if (ic1 >= 0) nl = max(nl, lv[ic1] + 1);
      if (val && nl != lv[tid]) { lv[tid] = nl; changed = 1; }
      __syncthreads();
      if (!changed) break;
    }
    if (val) { level[g] = lv[tid]; localMax = max(localMax, lv[tid]); }
    __syncthreads();
  }
  atomicMax(&smax, localMax);
  __syncthreads();
  if (tid == 0) nLevels[0] = smax + 1;
}

__global__ void sort_kernel(const int* __restrict__ level, const int* __restrict__ nLevels,
                            int* __restrict__ hist, int* __restrict__ cursor,
                            int* __restrict__ levelStart, int* __restrict__ levelList) {
  const int tid = threadIdx.x;
  const int nL = nLevels[0];
  for (int i = tid; i < NG; i += 1024) { hist[i] = 0; cursor[i] = 0; }
  __syncthreads();
  for (int g = tid; g < NG; g += 1024) atomicAdd(&hist[level[g]], 1);
  __syncthreads();
  if (tid == 0) {
    int acc = 0;
    for (int i = 0; i < nL; ++i) {
      int h = hist[i];
      levelStart[i] = acc;
      acc += h;
    }
    levelStart[nL] = acc;
  }
  __syncthreads();
  for (int g = tid; g < NG; g += 1024) {
    int l = level[g];
    int off = atomicAdd(&cursor[l], 1);
    levelList[levelStart[l] + off] = g;
  }
}

// Distributed sense-epoch grid barrier; no cache invalidation (all shared
// data goes through LLC-coherent relaxed atomics).
__device__ __forceinline__ void grid_bar(int* go, int* arr, int& epoch) {
  ++epoch;
  __syncthreads();   // all waves' atomic stores complete (vmcnt drained)
  if (blockIdx.x == 0) {
    const int t = threadIdx.x;
    if (t >= 1 && t < NB) {
      while (__hip_atomic_load(arr + t * 32, __ATOMIC_RELAXED, __HIP_MEMORY_SCOPE_AGENT) < epoch)
        __builtin_amdgcn_s_sleep(1);
    }
    __syncthreads();
    if (t == 0)
      __hip_atomic_store(go, epoch, __ATOMIC_RELEASE, __HIP_MEMORY_SCOPE_AGENT);
  } else {
    if (threadIdx.x == 0) {
      __hip_atomic_store(arr + blockIdx.x * 32, epoch, __ATOMIC_RELEASE, __HIP_MEMORY_SCOPE_AGENT);
      while (__hip_atomic_load(go, __ATOMIC_RELAXED, __HIP_MEMORY_SCOPE_AGENT) < epoch)
        __builtin_amdgcn_s_sleep(1);
    }
    __syncthreads();
  }
  asm volatile("" ::: "memory");
}

__global__ __launch_bounds__(BLK, 8)
void game_levels_kernel(const float* __restrict__ Wp,   const float* __restrict__ bp,
                        const float* __restrict__ W_ih, const float* __restrict__ b_ih,
                        const float* __restrict__ W_hh, const float* __restrict__ b_hh,
                        const float* __restrict__ ln_g, const float* __restrict__ ln_b,
                        const float* __restrict__ Wi1,  const float* __restrict__ bi1,
                        const float* __restrict__ Wi2,  const float* __restrict__ bi2,
                        const float* __restrict__ fA,   const float* __restrict__ fB,
                        const int* __restrict__ team_a, const int* __restrict__ team_b,
                        const int* __restrict__ a_won,
                        float* __restrict__ emb, float* __restrict__ ctx,
                        const int* __restrict__ levelStart, const int* __restrict__ levelList,
                        const int* __restrict__ nLevels,
                        float* __restrict__ nhbuf, float* __restrict__ hidbuf,
                        int* __restrict__ go, int* __restrict__ arr, int Wcap) {
  const int b    = blockIdx.x;
  const int tid  = threadIdx.x;
  const int lane = tid & 63;
  const int wave = tid >> 6;
  const int half = lane >> 5;   // phase A: row; phase C: 0=ih, 1=hh
  const int l5   = lane & 31;
  const int d0   = b;           // owned proj/gate dim
  const bool hasB1 = (b >= 256);
  const int r_b  = (b >> 7) & 1;
  const int h_b  = b & 127;

  __shared__ float wp[NCIN];
  __shared__ float wih[3 * ND];
  __shared__ float whh[3 * ND];
  __shared__ float wi1[ND];
  __shared__ float sImp[2];
  __shared__ float sRed[2][16];
  __shared__ float sStat[4];

  // ---- weight slices into LDS (once) ----
  for (int e = tid; e < NCIN; e += BLK) wp[e] = Wp[(size_t)d0 * NCIN + e];
  if (tid < ND) {
    const int e = tid;
#pragma unroll
    for (int gt = 0; gt < 3; ++gt) {
      wih[gt * ND + e] = W_ih[((size_t)gt * ND + d0) * ND + e];
      whh[gt * ND + e] = W_hh[((size_t)gt * ND + d0) * ND + e];
    }
    wi1[e] = hasB1 ? Wi1[(size_t)h_b * ND + e] : 0.f;
  }
  const float bp0 = bp[d0];
  const float bih0 = b_ih[d0], bih1 = b_ih[ND + d0], bih2 = b_ih[2 * ND + d0];
  const float bhh0 = b_hh[d0], bhh1 = b_hh[ND + d0], bhh2 = b_hh[2 * ND + d0];
  const float bi1h = hasB1 ? bi1[h_b] : 0.f;
  const float bi2v = bi2[0];
  const float2 w2p = ((const float2*)Wi2)[lane];
  float2 lg2 = make_float2(0.f, 0.f), lb2 = lg2;
  if (tid < 512) {
    lg2 = ((const float2*)ln_g)[tid & 255];
    lb2 = ((const float2*)ln_b)[tid & 255];
  }
  __syncthreads();

  const int nL = nLevels[0];
  int epoch = 0;

  for (int L = 0; L < nL; ++L) {
    const int s = levelStart[L], e_ = levelStart[L + 1];
    for (int cs = s; cs < e_; cs += Wcap) {
      const int W = min(e_ - cs, Wcap);

      // ===== phase A: proj[row][d0] (row = lane half) -> ctx =====
      for (int w = wave; w < W; w += 16) {
        const int g = levelList[cs + w];
        const int ta = team_a[g], tb = team_b[g];
        const float aw = (float)a_won[g];
        const float* eA = emb + (size_t)ta * ND;
        const float* eB = emb + (size_t)tb * ND;
        const float* fp = (half ? fB : fA) + (size_t)g * NF;
        float a0 = 0.f;
#pragma unroll
        for (int k = 0; k < 8; ++k) {
          const int e = k * 64 + 2 * l5;
          const float2 va = aload_f2(eA + e);
          const float2 vb = aload_f2(eB + e);
          const float2 w1 = *(const float2*)&wp[e];
          const float2 w2 = *(const float2*)&wp[ND + e];
          const float2 c1 = half ? vb : va;   // e_self
          const float2 c2 = half ? va : vb;   // e_opp
          a0 = fmaf(c1.x, w1.x, a0); a0 = fmaf(c1.y, w1.y, a0);
          a0 = fmaf(c2.x, w2.x, a0); a0 = fmaf(c2.y, w2.y, a0);
        }
        if (l5 < NF + 1) {
          const float cv = (l5 < NF) ? fp[l5] : (half ? 1.0f - aw : aw);
          a0 = fmaf(cv, wp[2 * ND + l5], a0);
        }
#pragma unroll
        for (int off = 16; off > 0; off >>= 1) a0 += __shfl_xor(a0, off);
        if (l5 == 0)
          astore_f(ctx + (size_t)g * 1024 + half * ND + d0, fmaxf(a0 + bp0, 0.f));
      }
      grid_bar(go, arr, epoch);

      // ===== phase C: gates -> new_h[row][d0]; B1: hidden (blocks>=256) =====
      for (int t = wave; t < 2 * W; t += 16) {
        const int w = t >> 1, row = t & 1;
        const int g = levelList[cs + w];
        const int team = row ? team_b[g] : team_a[g];
        const float* ep = emb + (size_t)team * ND;
        float e0v = 0.f;
        if (lane == 0) e0v = aload_f(ep + d0);   // issue early
        const float* src = half ? ep : (ctx + (size_t)g * 1024 + (size_t)row * ND);
        const float* wb = half ? whh : wih;
        float ac0 = 0.f, ac1 = 0.f, ac2 = 0.f;
#pragma unroll
        for (int k = 0; k < 8; ++k) {
          const int e = k * 64 + 2 * l5;
          const float2 sv = aload_f2(src + e);
          const float2 q0 = *(const float2*)&wb[e];
          const float2 q1 = *(const float2*)&wb[ND + e];
          const float2 q2 = *(const float2*)&wb[2 * ND + e];
          ac0 = fmaf(sv.x, q0.x, ac0); ac0 = fmaf(sv.y, q0.y, ac0);
          ac1 = fmaf(sv.x, q1.x, ac1); ac1 = fmaf(sv.y, q1.y, ac1);
          ac2 = fmaf(sv.x, q2.x, ac2); ac2 = fmaf(sv.y, q2.y, ac2);
        }
#pragma unroll
        for (int off = 16; off > 0; off >>= 1) {
          ac0 += __shfl_xor(ac0, off);
          ac1 += __shfl_xor(ac1, off);
          ac2 += __shfl_xor(ac2, off);
        }
        const float h0 = __shfl_xor(ac0, 32);
        const float h1 = __shfl_xor(ac1, 32);
        const float h2 = __shfl_xor(ac2, 32);
        if (lane == 0) {
          const float r = sigmf(ac0 + bih0 + h0 + bhh0);
          const float z = sigmf(ac1 + bih1 + h1 + bhh1);
          const float n = tanhf(ac2 + bih2 + r * (h2 + bhh2));
          astore_f(nhbuf + (size_t)w * 1024 + (size_t)row * ND + d0,
                   (1.f - z) * n + z * e0v);
        }
      }
      if (hasB1) {
        for (int w = wave; w < W; w += 16) {
          const int g = levelList[cs + w];
          const float* projp = ctx + (size_t)g * 1024 + (size_t)r_b * ND;
          float acc = 0.f;
#pragma unroll
          for (int j = 0; j < 4; ++j) {
            const int e = j * 128 + 2 * lane;
            const float2 pv = aload_f2(projp + e);
            acc = fmaf(pv.x, wi1[e], acc);
            acc = fmaf(pv.y, wi1[e + 1], acc);
          }
#pragma unroll
          for (int off = 32; off > 0; off >>= 1) acc += __shfl_xor(acc, off);
          if (lane == 0)
            astore_f(hidbuf + (size_t)w * 256 + r_b * NH + h_b, fmaxf(acc + bi1h, 0.f));
        }
      }
      grid_bar(go, arr, epoch);

      // ===== phase D (owner block per game): imp, blend, LN, emb write =====
      for (int w = b; w < W; w += NB) {
        const int g = levelList[cs + w];
        const int ta = team_a[g], tb = team_b[g];
        if (wave < 2) {
          const float2 hv = aload_f2(hidbuf + (size_t)w * 256 + wave * NH + 2 * lane);
          float acc = hv.x * w2p.x;
          acc = fmaf(hv.y, w2p.y, acc);
#pragma unroll
          for (int off = 32; off > 0; off >>= 1) acc += __shfl_xor(acc, off);
          if (lane == 0) sImp[wave] = sigmf(acc + bi2v);
        }
        __syncthreads();
        float ux = 0.f, uy = 0.f;
        if (tid < 512) {
          const int row = tid >> 8;
          const int e = 2 * (tid & 255);
          const int team = row ? tb : ta;
          const float imp = sImp[row];
          const float2 ev = aload_f2(emb + (size_t)team * ND + e);
          const float2 nv = aload_f2(nhbuf + (size_t)w * 1024 + (size_t)row * ND + e);
          ux = ev.x + imp * (nv.x - ev.x);
          uy = ev.y + imp * (nv.y - ev.y);
        }
        float sS = ux + uy, sQ = ux * ux + uy * uy;
#pragma unroll
        for (int off = 32; off > 0; off >>= 1) {
          sS += __shfl_xor(sS, off);
          sQ += __shfl_xor(sQ, off);
        }
        if (lane == 0) { sRed[0][wave] = sS; sRed[1][wave] = sQ; }
        __syncthreads();
        if (tid == 0) {
          const float S0 = sRed[0][0] + sRed[0][1] + sRed[0][2] + sRed[0][3];
          const float Q0 = sRed[1][0] + sRed[1][1] + sRed[1][2] + sRed[1][3];
          const float S1 = sRed[0][4] + sRed[0][5] + sRed[0][6] + sRed[0][7];
          const float Q1 = sRed[1][4] + sRed[1][5] + sRed[1][6] + sRed[1][7];
          const float mu0 = S0 * (1.0f / ND), mu1 = S1 * (1.0f / ND);
          const float v0 = Q0 * (1.0f / ND) - mu0 * mu0;
          const float v1 = Q1 * (1.0f / ND) - mu1 * mu1;
          sStat[0] = mu0; sStat[1] = 1.0f / sqrtf(v0 + 1e-5f);
          sStat[2] = mu1; sStat[3] = 1.0f / sqrtf(v1 + 1e-5f);
        }
        __syncthreads();
        if (tid < 512) {
          const int row = tid >> 8;
          const int e = 2 * (tid & 255);
          const float mu = sStat[row * 2], rs = sStat[row * 2 + 1];
          const float ox = (ux - mu) * rs * lg2.x + lb2.x;
          const float oy = (uy - mu) * rs * lg2.y + lb2.y;
          if (row == 0) {
            if (ta != tb) astore_f2(emb + (size_t)ta * ND + e, ox, oy);
          } else {
            astore_f2(emb + (size_t)tb * ND + e, ox, oy);
          }
        }
        __syncthreads();
      }
      grid_bar(go, arr, epoch);
    }
  }
}

extern "C" void kernel_launch(void* const* d_in, const int* in_sizes, int n_in,
                              void* d_out, int out_size, void* d_ws, size_t ws_size,
                              hipStream_t stream) {
  const float* emb_table = (const float*)d_in[0];
  const float* Wp    = (const float*)d_in[1];
  const float* bp    = (const float*)d_in[2];
  const float* W_ih  = (const float*)d_in[3];
  const float* b_ih  = (const float*)d_in[4];
  const float* W_hh  = (const float*)d_in[5];
  const float* b_hh  = (const float*)d_in[6];
  const float* ln_g  = (const float*)d_in[7];
  const float* ln_b  = (const float*)d_in[8];
  const float* Wi1   = (const float*)d_in[9];
  const float* bi1   = (const float*)d_in[10];
  const float* Wi2   = (const float*)d_in[11];
  const float* bi2   = (const float*)d_in[12];
  const float* fA    = (const float*)d_in[13];
  const float* fB    = (const float*)d_in[14];
  const int*   team_a = (const int*)d_in[15];
  const int*   team_b = (const int*)d_in[16];
  const int*   a_won  = (const int*)d_in[17];

  float* out = (float*)d_out;
  float* emb = out;
  float* ctx = out + (size_t)NT * ND;

  int* ip         = (int*)d_ws;
  int* go         = ip;                 // line 0
  int* arr        = ip + 32;            // NB lines, 128B apart
  int* nLevels    = ip + 32 + NB * 32;
  int* dep0       = nLevels + 32;
  int* dep1       = dep0 + NG;
  int* level      = dep1 + NG;
  int* hist       = level + NG;
  int* cursor     = hist + NG;
  int* levelStart = cursor + NG;
  int* levelList  = levelStart + NG + 2;
  const int flagInts = 32 + NB * 32;
  size_t control = (size_t)((char*)(levelList + NG) - (char*)d_ws);
  control = (control + 255) & ~(size_t)255;

  int Wcap = 1024;
  if (ws_size > control + 4096) {
    size_t avail = (ws_size - control) / ((size_t)(1024 + 256) * sizeof(float));
    if (avail < (size_t)Wcap) Wcap = (int)avail;
  } else {
    Wcap = 8;
  }
  if (Wcap < 8) Wcap = 8;
  float* nhbuf  = (float*)((char*)d_ws + control);
  float* hidbuf = nhbuf + (size_t)Wcap * 1024;

  hipMemcpyAsync(emb, emb_table, (size_t)NT * ND * sizeof(float),
                 hipMemcpyDeviceToDevice, stream);
  zero_kernel<<<(flagInts + 255) / 256, 256, 0, stream>>>(ip, flagInts);
  deps_kernel<<<(NG + 255) / 256, 256, 0, stream>>>(team_a, team_b, dep0, dep1);
  levels_kernel<<<1, 1024, 0, stream>>>(dep0, dep1, level, nLevels);
  sort_kernel<<<1, 1024, 0, stream>>>(level, nLevels, hist, cursor, levelStart, levelList);
  game_levels_kernel<<<NB, BLK, 0, stream>>>(
      Wp, bp, W_ih, b_ih, W_hh, b_hh, ln_g, ln_b, Wi1, bi1, Wi2, bi2,
      fA, fB, team_a, team_b, a_won, emb, ctx,
      levelStart, levelList, nLevels, nhbuf, hidbuf, go, arr, Wcap);
}